// Round 2
// baseline (551.577 us; speedup 1.0000x reference)
//
#include <hip/hip_runtime.h>

// Problem constants (from reference)
#define BN     16
#define NLINES 200
#define CFEAT  64
#define HIMG   256
#define WIMG   256
#define LLEN   64
#define NBINS  32

// Output element offsets (flat concat, return order)
#define O_NORM   0         // (B,N,2)      6400
#define O_CIMG   6400      // (B,N,2)      6400
#define O_CBODY  12800     // (B,N,3)      9600
#define O_PF     22400     // (B,N,64)   204800
#define O_PB     227200    // (B,N,64)   204800
#define O_VALID  432000    // (B,N)        3200
#define O_AMP    435200    // (B,N)        3200
#define O_SLOPE  438400    // (B,N)        3200
#define O_FEAT   441600    // (B,64,200,64) 13107200

struct LineGeom {
  float cix, ciy;   // centers_in_image
  float nix, niy;   // normals_in_image
  float cb0, cb1, cb2;
  bool  vdl;
};

__device__ __forceinline__ LineGeom compute_line(
    const float* __restrict__ pose, const float* __restrict__ cam,
    const float* __restrict__ tv, int b, int n)
{
  const float* P = pose + b*12;
  float R00=P[0],R01=P[1],R02=P[2];
  float R10=P[3],R11=P[4],R12=P[5];
  float R20=P[6],R21=P[7],R22=P[8];
  float t0=P[9], t1=P[10], t2=P[11];
  const float* C = cam + b*6;
  float sx=C[0], sy=C[1], fx=C[2], fy=C[3];
  float cx=C[4], cy=C[5];
  const float* T = tv + (b*NLINES + n)*8;
  float cb0=T[0], cb1=T[1], cb2=T[2];
  float nb0=T[3], nb1=T[4], nb2=T[5];
  float fg=T[6],  bg=T[7];

  // einsum 'bnj,bij->bni': out_i = sum_j v_j * R[i][j]
  float cv0 = R00*cb0 + R01*cb1 + R02*cb2 + t0;
  float cv1 = R10*cb0 + R11*cb1 + R12*cb2 + t1;
  float cv2 = R20*cb0 + R21*cb1 + R22*cb2 + t2;
  float nv0 = R00*nb0 + R01*nb1 + R02*nb2;
  float nv1 = R10*nb0 + R11*nb1 + R12*nb2;

  float z  = cv2;
  float zc = fmaxf(z, 1e-4f);
  float cix = (cv0/zc)*fx + cx;
  float ciy = (cv1/zc)*fy + cy;
  bool inb = (cix >= 0.f) && (cix <= sx - 1.f) && (ciy >= 0.f) && (ciy <= sy - 1.f);
  bool centers_valid = (z > 1e-4f) && inb;

  float nrm = fmaxf(sqrtf(nv0*nv0 + nv1*nv1), 1e-12f);
  float nix = nv0/nrm, niy = nv1/nrm;

  float contd = fminf(fg*fx/z, bg*fx/z);
  bool vdl = (contd >= 6.0f) && centers_valid;

  // endpoint in-bounds check on raw points (strict < 256)
  float px0 = cix + (-31.5f)*nix, py0 = ciy + (-31.5f)*niy;
  float px1 = cix + ( 31.5f)*nix, py1 = ciy + ( 31.5f)*niy;
  vdl = vdl && (px0 >= 0.f) && (px0 < 256.f) && (py0 >= 0.f) && (py0 < 256.f)
            && (px1 >= 0.f) && (px1 < 256.f) && (py1 >= 0.f) && (py1 < 256.f);

  LineGeom g;
  g.cix = cix; g.ciy = ciy; g.nix = nix; g.niy = niy;
  g.cb0 = cb0; g.cb1 = cb1; g.cb2 = cb2; g.vdl = vdl;
  return g;
}

// Replicate reference f32 chain: point -> grid -> unnorm (== p - 0.5 up to ulps)
__device__ __forceinline__ void point_xy(const LineGeom& g, int i, float& x, float& y)
{
  float s  = (float)i - 31.5f;
  float px = g.cix + s*g.nix;
  float py = g.ciy + s*g.niy;
  float gx = px/256.0f*2.0f - 1.0f;
  float gy = py/256.0f*2.0f - 1.0f;
  x = ((gx + 1.0f)*256.0f - 1.0f)*0.5f;
  y = ((gy + 1.0f)*256.0f - 1.0f)*0.5f;
}

// Kernel A: per-point nearest sample -> hist -> pf/pb, plus per-line outputs
__global__ __launch_bounds__(256)
void contour_points_kernel(const float* __restrict__ image,
                           const float* __restrict__ pose,
                           const float* __restrict__ cam,
                           const float* __restrict__ tv,
                           const float* __restrict__ fore,
                           const float* __restrict__ back,
                           float* __restrict__ out)
{
  int tid = blockIdx.x*256 + threadIdx.x;   // 0 .. 204799, grid exact
  int i  = tid & 63;
  int ln = tid >> 6;          // 0..3199
  int n  = ln % NLINES;
  int b  = ln / NLINES;

  LineGeom g = compute_line(pose, cam, tv, b, n);

  float x, y;
  point_xy(g, i, x, y);

  // nearest-neighbor sample of image (3 channels)
  float xr = rintf(x), yr = rintf(y);       // jnp.round = half-to-even
  int xi = (int)xr, yi = (int)yr;
  bool v = (xi >= 0) && (xi < WIMG) && (yi >= 0) && (yi < HIMG);
  int xc = min(max(xi, 0), WIMG-1), yc = min(max(yi, 0), HIMG-1);
  const float* ib = image + (size_t)b*3*HIMG*WIMG + yc*WIMG + xc;
  float r0 = v ? ib[0]           : 0.f;
  float r1 = v ? ib[HIMG*WIMG]   : 0.f;
  float r2 = v ? ib[2*HIMG*WIMG] : 0.f;

  int b0 = min(max((int)(r0*32.f), 0), NBINS-1);
  int b1 = min(max((int)(r1*32.f), 0), NBINS-1);
  int b2 = min(max((int)(r2*32.f), 0), NBINS-1);
  int hidx = (b0*NBINS + b1)*NBINS + b2;

  float pf = fore[b*NBINS*NBINS*NBINS + hidx];
  float pb = back[b*NBINS*NBINS*NBINS + hidx];
  if (pf < 1e-5f && pb < 1e-5f) { pf = 1e-5f; pb = 1e-5f; }
  float ps = pf + pb;
  pf /= ps; pb /= ps;

  out[O_PF + ln*LLEN + i] = pf;
  out[O_PB + ln*LLEN + i] = pb;

  if (i == 0) {
    out[O_NORM  + ln*2 + 0] = g.nix;
    out[O_NORM  + ln*2 + 1] = g.niy;
    out[O_CIMG  + ln*2 + 0] = g.cix;
    out[O_CIMG  + ln*2 + 1] = g.ciy;
    out[O_CBODY + ln*3 + 0] = g.cb0;
    out[O_CBODY + ln*3 + 1] = g.cb1;
    out[O_CBODY + ln*3 + 2] = g.cb2;
    out[O_VALID + ln] = g.vdl ? 1.0f : 0.0f;
    out[O_AMP   + ln] = 0.43f;
    out[O_SLOPE + ln] = 0.5f;
  }
}

// Kernel B: bilinear feature sampling -> lines_feature (B,64,200,64)
// One block per line; thread t: point i = t&63, wave w = t>>6 handles c = w*16+k
__global__ __launch_bounds__(256)
void contour_feature_kernel(const float* __restrict__ feature,
                            const float* __restrict__ pose,
                            const float* __restrict__ cam,
                            const float* __restrict__ tv,
                            float* __restrict__ out)
{
  int ln = blockIdx.x;        // 0..3199
  int n  = ln % NLINES;
  int b  = ln / NLINES;
  int t  = threadIdx.x;
  int i  = t & 63;
  int w  = t >> 6;            // 0..3

  LineGeom g = compute_line(pose, cam, tv, b, n);
  float x, y;
  point_xy(g, i, x, y);

  float x0f = floorf(x), y0f = floorf(y);
  float wx1 = x - x0f, wy1 = y - y0f;
  float wx0 = 1.0f - wx1, wy0 = 1.0f - wy1;
  int x0 = (int)x0f, y0 = (int)y0f;
  int x1 = x0 + 1,  y1 = y0 + 1;
  bool vx0 = (x0 >= 0) && (x0 < WIMG);
  bool vx1 = (x1 >= 0) && (x1 < WIMG);
  bool vy0 = (y0 >= 0) && (y0 < HIMG);
  bool vy1 = (y1 >= 0) && (y1 < HIMG);
  float w00 = wx0*wy0 * ((vx0 && vy0) ? 1.f : 0.f);
  float w10 = wx1*wy0 * ((vx1 && vy0) ? 1.f : 0.f);
  float w01 = wx0*wy1 * ((vx0 && vy1) ? 1.f : 0.f);
  float w11 = wx1*wy1 * ((vx1 && vy1) ? 1.f : 0.f);
  int xc0 = min(max(x0,0), WIMG-1), xc1 = min(max(x1,0), WIMG-1);
  int yc0 = min(max(y0,0), HIMG-1), yc1 = min(max(y1,0), HIMG-1);
  int off00 = yc0*WIMG + xc0;
  int off10 = yc0*WIMG + xc1;
  int off01 = yc1*WIMG + xc0;
  int off11 = yc1*WIMG + xc1;

  const float* fbase = feature + (size_t)b*CFEAT*HIMG*WIMG;
  size_t obase = (size_t)O_FEAT + (((size_t)b*CFEAT)*NLINES + n)*LLEN + i;

  #pragma unroll
  for (int k = 0; k < 16; ++k) {
    int c = w*16 + k;
    const float* fc = fbase + (size_t)c*HIMG*WIMG;
    float val = w00*fc[off00] + w10*fc[off10]
              + w01*fc[off01] + w11*fc[off11];
    out[obase + (size_t)c*NLINES*LLEN] = val;
  }
}

extern "C" void kernel_launch(void* const* d_in, const int* in_sizes, int n_in,
                              void* d_out, int out_size, void* d_ws, size_t ws_size,
                              hipStream_t stream) {
  const float* image   = (const float*)d_in[0];
  const float* feature = (const float*)d_in[1];
  const float* pose    = (const float*)d_in[2];
  const float* cam     = (const float*)d_in[3];
  const float* tv      = (const float*)d_in[4];
  const float* fore    = (const float*)d_in[5];
  const float* back    = (const float*)d_in[6];
  float* out = (float*)d_out;

  // Kernel A: 16*200*64 = 204800 threads
  contour_points_kernel<<<(BN*NLINES*LLEN)/256, 256, 0, stream>>>(
      image, pose, cam, tv, fore, back, out);

  // Kernel B: one block per line
  contour_feature_kernel<<<BN*NLINES, 256, 0, stream>>>(
      feature, pose, cam, tv, out);
}

// Round 3
// 439.115 us; speedup vs baseline: 1.2561x; 1.2561x over previous
//
#include <hip/hip_runtime.h>

// Problem constants (from reference)
#define BN     16
#define NLINES 200
#define CFEAT  64
#define HIMG   256
#define WIMG   256
#define LLEN   64
#define NBINS  32

// Output element offsets (flat concat, return order)
#define O_NORM   0         // (B,N,2)      6400
#define O_CIMG   6400      // (B,N,2)      6400
#define O_CBODY  12800     // (B,N,3)      9600
#define O_PF     22400     // (B,N,64)   204800
#define O_PB     227200    // (B,N,64)   204800
#define O_VALID  432000    // (B,N)        3200
#define O_AMP    435200    // (B,N)        3200
#define O_SLOPE  438400    // (B,N)        3200
#define O_FEAT   441600    // (B,64,200,64) 13107200

#define NPTS (BN*NLINES*LLEN)   // 204800 points

struct LineGeom {
  float cix, ciy;   // centers_in_image
  float nix, niy;   // normals_in_image
  float cb0, cb1, cb2;
  bool  vdl;
};

__device__ __forceinline__ LineGeom compute_line(
    const float* __restrict__ pose, const float* __restrict__ cam,
    const float* __restrict__ tv, int b, int n)
{
  const float* P = pose + b*12;
  float R00=P[0],R01=P[1],R02=P[2];
  float R10=P[3],R11=P[4],R12=P[5];
  float R20=P[6],R21=P[7],R22=P[8];
  float t0=P[9], t1=P[10], t2=P[11];
  const float* C = cam + b*6;
  float sx=C[0], sy=C[1], fx=C[2], fy=C[3];
  float cx=C[4], cy=C[5];
  const float* T = tv + (b*NLINES + n)*8;
  float cb0=T[0], cb1=T[1], cb2=T[2];
  float nb0=T[3], nb1=T[4], nb2=T[5];
  float fg=T[6],  bg=T[7];

  float cv0 = R00*cb0 + R01*cb1 + R02*cb2 + t0;
  float cv1 = R10*cb0 + R11*cb1 + R12*cb2 + t1;
  float cv2 = R20*cb0 + R21*cb1 + R22*cb2 + t2;
  float nv0 = R00*nb0 + R01*nb1 + R02*nb2;
  float nv1 = R10*nb0 + R11*nb1 + R12*nb2;

  float z  = cv2;
  float zc = fmaxf(z, 1e-4f);
  float cix = (cv0/zc)*fx + cx;
  float ciy = (cv1/zc)*fy + cy;
  bool inb = (cix >= 0.f) && (cix <= sx - 1.f) && (ciy >= 0.f) && (ciy <= sy - 1.f);
  bool centers_valid = (z > 1e-4f) && inb;

  float nrm = fmaxf(sqrtf(nv0*nv0 + nv1*nv1), 1e-12f);
  float nix = nv0/nrm, niy = nv1/nrm;

  float contd = fminf(fg*fx/z, bg*fx/z);
  bool vdl = (contd >= 6.0f) && centers_valid;

  float px0 = cix + (-31.5f)*nix, py0 = ciy + (-31.5f)*niy;
  float px1 = cix + ( 31.5f)*nix, py1 = ciy + ( 31.5f)*niy;
  vdl = vdl && (px0 >= 0.f) && (px0 < 256.f) && (py0 >= 0.f) && (py0 < 256.f)
            && (px1 >= 0.f) && (px1 < 256.f) && (py1 >= 0.f) && (py1 < 256.f);

  LineGeom g;
  g.cix = cix; g.ciy = ciy; g.nix = nix; g.niy = niy;
  g.cb0 = cb0; g.cb1 = cb1; g.cb2 = cb2; g.vdl = vdl;
  return g;
}

__device__ __forceinline__ void point_xy(const LineGeom& g, int i, float& x, float& y)
{
  float s  = (float)i - 31.5f;
  float px = g.cix + s*g.nix;
  float py = g.ciy + s*g.niy;
  float gx = px/256.0f*2.0f - 1.0f;
  float gy = py/256.0f*2.0f - 1.0f;
  x = ((gx + 1.0f)*256.0f - 1.0f)*0.5f;
  y = ((gy + 1.0f)*256.0f - 1.0f)*0.5f;
}

// Shared body for the per-point kernel; PRE=true also writes bilinear precompute.
template <bool PRE>
__device__ __forceinline__ void points_body(const float* __restrict__ image,
                                            const float* __restrict__ pose,
                                            const float* __restrict__ cam,
                                            const float* __restrict__ tv,
                                            const float* __restrict__ fore,
                                            const float* __restrict__ back,
                                            float* __restrict__ out,
                                            int4*  __restrict__ offs,
                                            float4* __restrict__ wts)
{
  int tid = blockIdx.x*256 + threadIdx.x;   // 0 .. 204799, grid exact
  int i  = tid & 63;
  int ln = tid >> 6;          // 0..3199
  int n  = ln % NLINES;
  int b  = ln / NLINES;

  LineGeom g = compute_line(pose, cam, tv, b, n);

  float x, y;
  point_xy(g, i, x, y);

  // nearest-neighbor sample of image (3 channels) -> hist -> pf/pb
  float xr = rintf(x), yr = rintf(y);       // jnp.round = half-to-even
  int xi = (int)xr, yi = (int)yr;
  bool v = (xi >= 0) && (xi < WIMG) && (yi >= 0) && (yi < HIMG);
  int xc = min(max(xi, 0), WIMG-1), yc = min(max(yi, 0), HIMG-1);
  const float* ib = image + (size_t)b*3*HIMG*WIMG + yc*WIMG + xc;
  float r0 = v ? ib[0]           : 0.f;
  float r1 = v ? ib[HIMG*WIMG]   : 0.f;
  float r2 = v ? ib[2*HIMG*WIMG] : 0.f;

  int b0 = min(max((int)(r0*32.f), 0), NBINS-1);
  int b1 = min(max((int)(r1*32.f), 0), NBINS-1);
  int b2 = min(max((int)(r2*32.f), 0), NBINS-1);
  int hidx = (b0*NBINS + b1)*NBINS + b2;

  float pf = fore[b*NBINS*NBINS*NBINS + hidx];
  float pb = back[b*NBINS*NBINS*NBINS + hidx];
  if (pf < 1e-5f && pb < 1e-5f) { pf = 1e-5f; pb = 1e-5f; }
  float ps = pf + pb;
  pf /= ps; pb /= ps;

  out[O_PF + ln*LLEN + i] = pf;
  out[O_PB + ln*LLEN + i] = pb;

  if (i == 0) {
    out[O_NORM  + ln*2 + 0] = g.nix;
    out[O_NORM  + ln*2 + 1] = g.niy;
    out[O_CIMG  + ln*2 + 0] = g.cix;
    out[O_CIMG  + ln*2 + 1] = g.ciy;
    out[O_CBODY + ln*3 + 0] = g.cb0;
    out[O_CBODY + ln*3 + 1] = g.cb1;
    out[O_CBODY + ln*3 + 2] = g.cb2;
    out[O_VALID + ln] = g.vdl ? 1.0f : 0.0f;
    out[O_AMP   + ln] = 0.43f;
    out[O_SLOPE + ln] = 0.5f;
  }

  if (PRE) {
    float x0f = floorf(x), y0f = floorf(y);
    float wx1 = x - x0f, wy1 = y - y0f;
    float wx0 = 1.0f - wx1, wy0 = 1.0f - wy1;
    int x0 = (int)x0f, y0 = (int)y0f;
    int x1 = x0 + 1,  y1 = y0 + 1;
    bool vx0 = (x0 >= 0) && (x0 < WIMG);
    bool vx1 = (x1 >= 0) && (x1 < WIMG);
    bool vy0 = (y0 >= 0) && (y0 < HIMG);
    bool vy1 = (y1 >= 0) && (y1 < HIMG);
    float4 w;
    w.x = wx0*wy0 * ((vx0 && vy0) ? 1.f : 0.f);
    w.y = wx1*wy0 * ((vx1 && vy0) ? 1.f : 0.f);
    w.z = wx0*wy1 * ((vx0 && vy1) ? 1.f : 0.f);
    w.w = wx1*wy1 * ((vx1 && vy1) ? 1.f : 0.f);
    int xc0 = min(max(x0,0), WIMG-1), xc1 = min(max(x1,0), WIMG-1);
    int yc0 = min(max(y0,0), HIMG-1), yc1 = min(max(y1,0), HIMG-1);
    int4 o;
    o.x = yc0*WIMG + xc0;
    o.y = yc0*WIMG + xc1;
    o.z = yc1*WIMG + xc0;
    o.w = yc1*WIMG + xc1;
    offs[tid] = o;
    wts[tid]  = w;
  }
}

__global__ __launch_bounds__(256)
void contour_points_pre_kernel(const float* __restrict__ image,
                               const float* __restrict__ pose,
                               const float* __restrict__ cam,
                               const float* __restrict__ tv,
                               const float* __restrict__ fore,
                               const float* __restrict__ back,
                               float* __restrict__ out,
                               int4*  __restrict__ offs,
                               float4* __restrict__ wts)
{
  points_body<true>(image, pose, cam, tv, fore, back, out, offs, wts);
}

__global__ __launch_bounds__(256)
void contour_points_kernel(const float* __restrict__ image,
                           const float* __restrict__ pose,
                           const float* __restrict__ cam,
                           const float* __restrict__ tv,
                           const float* __restrict__ fore,
                           const float* __restrict__ back,
                           float* __restrict__ out)
{
  points_body<false>(image, pose, cam, tv, fore, back, out, nullptr, nullptr);
}

// Kernel F: one thread per output feature element (b,c,n,i).
// tid == flat index into lines_feature (B,64,200,64). 4 gathers + 1 linear store.
__global__ __launch_bounds__(256)
void contour_gather_kernel(const float* __restrict__ feature,
                           const int4*  __restrict__ offs,
                           const float4* __restrict__ wts,
                           float* __restrict__ out)
{
  int tid  = blockIdx.x*256 + threadIdx.x;  // 0 .. 13107199, grid exact
  int i    = tid & 63;
  int rest = tid >> 6;            // (b*64+c)*200 + n
  int n    = rest % NLINES;
  int bc   = rest / NLINES;       // b*64 + c
  int b    = bc >> 6;

  int p = (b*NLINES + n)*LLEN + i;   // point index
  int4   o = offs[p];
  float4 w = wts[p];

  const float* fp = feature + ((size_t)bc << 16);  // plane (b,c) = 256*256
  float val = w.x*fp[o.x] + w.y*fp[o.y] + w.z*fp[o.z] + w.w*fp[o.w];
  out[O_FEAT + tid] = val;
}

// Fallback feature kernel (R2 structure), used only if ws is too small.
__global__ __launch_bounds__(256)
void contour_feature_kernel(const float* __restrict__ feature,
                            const float* __restrict__ pose,
                            const float* __restrict__ cam,
                            const float* __restrict__ tv,
                            float* __restrict__ out)
{
  int ln = blockIdx.x;
  int n  = ln % NLINES;
  int b  = ln / NLINES;
  int t  = threadIdx.x;
  int i  = t & 63;
  int w  = t >> 6;

  LineGeom g = compute_line(pose, cam, tv, b, n);
  float x, y;
  point_xy(g, i, x, y);

  float x0f = floorf(x), y0f = floorf(y);
  float wx1 = x - x0f, wy1 = y - y0f;
  float wx0 = 1.0f - wx1, wy0 = 1.0f - wy1;
  int x0 = (int)x0f, y0 = (int)y0f;
  int x1 = x0 + 1,  y1 = y0 + 1;
  bool vx0 = (x0 >= 0) && (x0 < WIMG);
  bool vx1 = (x1 >= 0) && (x1 < WIMG);
  bool vy0 = (y0 >= 0) && (y0 < HIMG);
  bool vy1 = (y1 >= 0) && (y1 < HIMG);
  float w00 = wx0*wy0 * ((vx0 && vy0) ? 1.f : 0.f);
  float w10 = wx1*wy0 * ((vx1 && vy0) ? 1.f : 0.f);
  float w01 = wx0*wy1 * ((vx0 && vy1) ? 1.f : 0.f);
  float w11 = wx1*wy1 * ((vx1 && vy1) ? 1.f : 0.f);
  int xc0 = min(max(x0,0), WIMG-1), xc1 = min(max(x1,0), WIMG-1);
  int yc0 = min(max(y0,0), HIMG-1), yc1 = min(max(y1,0), HIMG-1);
  int off00 = yc0*WIMG + xc0;
  int off10 = yc0*WIMG + xc1;
  int off01 = yc1*WIMG + xc0;
  int off11 = yc1*WIMG + xc1;

  const float* fbase = feature + (size_t)b*CFEAT*HIMG*WIMG;
  size_t obase = (size_t)O_FEAT + (((size_t)b*CFEAT)*NLINES + n)*LLEN + i;

  #pragma unroll
  for (int k = 0; k < 16; ++k) {
    int c = w*16 + k;
    const float* fc = fbase + (size_t)c*HIMG*WIMG;
    float val = w00*fc[off00] + w10*fc[off10]
              + w01*fc[off01] + w11*fc[off11];
    out[obase + (size_t)c*NLINES*LLEN] = val;
  }
}

extern "C" void kernel_launch(void* const* d_in, const int* in_sizes, int n_in,
                              void* d_out, int out_size, void* d_ws, size_t ws_size,
                              hipStream_t stream) {
  const float* image   = (const float*)d_in[0];
  const float* feature = (const float*)d_in[1];
  const float* pose    = (const float*)d_in[2];
  const float* cam     = (const float*)d_in[3];
  const float* tv      = (const float*)d_in[4];
  const float* fore    = (const float*)d_in[5];
  const float* back    = (const float*)d_in[6];
  float* out = (float*)d_out;

  const size_t need = (size_t)NPTS * (sizeof(int4) + sizeof(float4)); // 6.55 MB
  if (ws_size >= need) {
    int4*   offs = (int4*)d_ws;
    float4* wts  = (float4*)((char*)d_ws + (size_t)NPTS*sizeof(int4));
    contour_points_pre_kernel<<<NPTS/256, 256, 0, stream>>>(
        image, pose, cam, tv, fore, back, out, offs, wts);
    contour_gather_kernel<<<(BN*CFEAT*NLINES*LLEN)/256, 256, 0, stream>>>(
        feature, offs, wts, out);
  } else {
    contour_points_kernel<<<NPTS/256, 256, 0, stream>>>(
        image, pose, cam, tv, fore, back, out);
    contour_feature_kernel<<<BN*NLINES, 256, 0, stream>>>(
        feature, pose, cam, tv, out);
  }
}

// Round 4
// 428.280 us; speedup vs baseline: 1.2879x; 1.0253x over previous
//
#include <hip/hip_runtime.h>

// Problem constants (from reference)
#define BN     16
#define NLINES 200
#define CFEAT  64
#define HIMG   256
#define WIMG   256
#define LLEN   64
#define NBINS  32

// Output element offsets (flat concat, return order)
#define O_NORM   0         // (B,N,2)      6400
#define O_CIMG   6400      // (B,N,2)      6400
#define O_CBODY  12800     // (B,N,3)      9600
#define O_PF     22400     // (B,N,64)   204800
#define O_PB     227200    // (B,N,64)   204800
#define O_VALID  432000    // (B,N)        3200
#define O_AMP    435200    // (B,N)        3200
#define O_SLOPE  438400    // (B,N)        3200
#define O_FEAT   441600    // (B,64,200,64) 13107200

#define NPTS (BN*NLINES*LLEN)   // 204800 points

struct LineGeom {
  float cix, ciy;   // centers_in_image
  float nix, niy;   // normals_in_image
  float cb0, cb1, cb2;
  bool  vdl;
};

__device__ __forceinline__ LineGeom compute_line(
    const float* __restrict__ pose, const float* __restrict__ cam,
    const float* __restrict__ tv, int b, int n)
{
  const float* P = pose + b*12;
  float R00=P[0],R01=P[1],R02=P[2];
  float R10=P[3],R11=P[4],R12=P[5];
  float R20=P[6],R21=P[7],R22=P[8];
  float t0=P[9], t1=P[10], t2=P[11];
  const float* C = cam + b*6;
  float sx=C[0], sy=C[1], fx=C[2], fy=C[3];
  float cx=C[4], cy=C[5];
  const float* T = tv + (b*NLINES + n)*8;
  float cb0=T[0], cb1=T[1], cb2=T[2];
  float nb0=T[3], nb1=T[4], nb2=T[5];
  float fg=T[6],  bg=T[7];

  float cv0 = R00*cb0 + R01*cb1 + R02*cb2 + t0;
  float cv1 = R10*cb0 + R11*cb1 + R12*cb2 + t1;
  float cv2 = R20*cb0 + R21*cb1 + R22*cb2 + t2;
  float nv0 = R00*nb0 + R01*nb1 + R02*nb2;
  float nv1 = R10*nb0 + R11*nb1 + R12*nb2;

  float z  = cv2;
  float zc = fmaxf(z, 1e-4f);
  float cix = (cv0/zc)*fx + cx;
  float ciy = (cv1/zc)*fy + cy;
  bool inb = (cix >= 0.f) && (cix <= sx - 1.f) && (ciy >= 0.f) && (ciy <= sy - 1.f);
  bool centers_valid = (z > 1e-4f) && inb;

  float nrm = fmaxf(sqrtf(nv0*nv0 + nv1*nv1), 1e-12f);
  float nix = nv0/nrm, niy = nv1/nrm;

  float contd = fminf(fg*fx/z, bg*fx/z);
  bool vdl = (contd >= 6.0f) && centers_valid;

  float px0 = cix + (-31.5f)*nix, py0 = ciy + (-31.5f)*niy;
  float px1 = cix + ( 31.5f)*nix, py1 = ciy + ( 31.5f)*niy;
  vdl = vdl && (px0 >= 0.f) && (px0 < 256.f) && (py0 >= 0.f) && (py0 < 256.f)
            && (px1 >= 0.f) && (px1 < 256.f) && (py1 >= 0.f) && (py1 < 256.f);

  LineGeom g;
  g.cix = cix; g.ciy = ciy; g.nix = nix; g.niy = niy;
  g.cb0 = cb0; g.cb1 = cb1; g.cb2 = cb2; g.vdl = vdl;
  return g;
}

__device__ __forceinline__ void point_xy(const LineGeom& g, int i, float& x, float& y)
{
  float s  = (float)i - 31.5f;
  float px = g.cix + s*g.nix;
  float py = g.ciy + s*g.niy;
  float gx = px/256.0f*2.0f - 1.0f;
  float gy = py/256.0f*2.0f - 1.0f;
  x = ((gx + 1.0f)*256.0f - 1.0f)*0.5f;
  y = ((gy + 1.0f)*256.0f - 1.0f)*0.5f;
}

// Shared body for the per-point kernel; PRE=true also writes bilinear precompute.
template <bool PRE>
__device__ __forceinline__ void points_body(const float* __restrict__ image,
                                            const float* __restrict__ pose,
                                            const float* __restrict__ cam,
                                            const float* __restrict__ tv,
                                            const float* __restrict__ fore,
                                            const float* __restrict__ back,
                                            float* __restrict__ out,
                                            int4*  __restrict__ offs,
                                            float4* __restrict__ wts)
{
  int tid = blockIdx.x*256 + threadIdx.x;   // 0 .. 204799, grid exact
  int i  = tid & 63;
  int ln = tid >> 6;          // 0..3199
  int n  = ln % NLINES;
  int b  = ln / NLINES;

  LineGeom g = compute_line(pose, cam, tv, b, n);

  float x, y;
  point_xy(g, i, x, y);

  // nearest-neighbor sample of image (3 channels) -> hist -> pf/pb
  float xr = rintf(x), yr = rintf(y);       // jnp.round = half-to-even
  int xi = (int)xr, yi = (int)yr;
  bool v = (xi >= 0) && (xi < WIMG) && (yi >= 0) && (yi < HIMG);
  int xc = min(max(xi, 0), WIMG-1), yc = min(max(yi, 0), HIMG-1);
  const float* ib = image + (size_t)b*3*HIMG*WIMG + yc*WIMG + xc;
  float r0 = v ? ib[0]           : 0.f;
  float r1 = v ? ib[HIMG*WIMG]   : 0.f;
  float r2 = v ? ib[2*HIMG*WIMG] : 0.f;

  int b0 = min(max((int)(r0*32.f), 0), NBINS-1);
  int b1 = min(max((int)(r1*32.f), 0), NBINS-1);
  int b2 = min(max((int)(r2*32.f), 0), NBINS-1);
  int hidx = (b0*NBINS + b1)*NBINS + b2;

  float pf = fore[b*NBINS*NBINS*NBINS + hidx];
  float pb = back[b*NBINS*NBINS*NBINS + hidx];
  if (pf < 1e-5f && pb < 1e-5f) { pf = 1e-5f; pb = 1e-5f; }
  float ps = pf + pb;
  pf /= ps; pb /= ps;

  out[O_PF + ln*LLEN + i] = pf;
  out[O_PB + ln*LLEN + i] = pb;

  if (i == 0) {
    out[O_NORM  + ln*2 + 0] = g.nix;
    out[O_NORM  + ln*2 + 1] = g.niy;
    out[O_CIMG  + ln*2 + 0] = g.cix;
    out[O_CIMG  + ln*2 + 1] = g.ciy;
    out[O_CBODY + ln*3 + 0] = g.cb0;
    out[O_CBODY + ln*3 + 1] = g.cb1;
    out[O_CBODY + ln*3 + 2] = g.cb2;
    out[O_VALID + ln] = g.vdl ? 1.0f : 0.0f;
    out[O_AMP   + ln] = 0.43f;
    out[O_SLOPE + ln] = 0.5f;
  }

  if (PRE) {
    float x0f = floorf(x), y0f = floorf(y);
    float wx1 = x - x0f, wy1 = y - y0f;
    float wx0 = 1.0f - wx1, wy0 = 1.0f - wy1;
    int x0 = (int)x0f, y0 = (int)y0f;
    int x1 = x0 + 1,  y1 = y0 + 1;
    bool vx0 = (x0 >= 0) && (x0 < WIMG);
    bool vx1 = (x1 >= 0) && (x1 < WIMG);
    bool vy0 = (y0 >= 0) && (y0 < HIMG);
    bool vy1 = (y1 >= 0) && (y1 < HIMG);
    float4 w;
    w.x = wx0*wy0 * ((vx0 && vy0) ? 1.f : 0.f);
    w.y = wx1*wy0 * ((vx1 && vy0) ? 1.f : 0.f);
    w.z = wx0*wy1 * ((vx0 && vy1) ? 1.f : 0.f);
    w.w = wx1*wy1 * ((vx1 && vy1) ? 1.f : 0.f);
    int xc0 = min(max(x0,0), WIMG-1), xc1 = min(max(x1,0), WIMG-1);
    int yc0 = min(max(y0,0), HIMG-1), yc1 = min(max(y1,0), HIMG-1);
    int4 o;
    o.x = yc0*WIMG + xc0;
    o.y = yc0*WIMG + xc1;
    o.z = yc1*WIMG + xc0;
    o.w = yc1*WIMG + xc1;
    offs[tid] = o;
    wts[tid]  = w;
  }
}

__global__ __launch_bounds__(256)
void contour_points_pre_kernel(const float* __restrict__ image,
                               const float* __restrict__ pose,
                               const float* __restrict__ cam,
                               const float* __restrict__ tv,
                               const float* __restrict__ fore,
                               const float* __restrict__ back,
                               float* __restrict__ out,
                               int4*  __restrict__ offs,
                               float4* __restrict__ wts)
{
  points_body<true>(image, pose, cam, tv, fore, back, out, offs, wts);
}

__global__ __launch_bounds__(256)
void contour_points_kernel(const float* __restrict__ image,
                           const float* __restrict__ pose,
                           const float* __restrict__ cam,
                           const float* __restrict__ tv,
                           const float* __restrict__ fore,
                           const float* __restrict__ back,
                           float* __restrict__ out)
{
  points_body<false>(image, pose, cam, tv, fore, back, out, nullptr, nullptr);
}

// Kernel F2: 2 channels per thread, XCD-affine block swizzle.
// Work unit u = (b, c2) plane-pair (512 units); each unit = 200*64 elems = 50 blocks.
// All 50 blocks of a unit map to the same XCD (bid%8 heuristic): the two 256 KB
// planes + the per-b offs/wts slice (~410 KB) stay resident in that XCD's 4 MB L2.
__global__ __launch_bounds__(256)
void contour_gather2_kernel(const float* __restrict__ feature,
                            const int4*  __restrict__ offs,
                            const float4* __restrict__ wts,
                            float* __restrict__ out)
{
  int bid = blockIdx.x;        // 0..25599
  int xcd = bid & 7;
  int q   = bid >> 3;          // 0..3199
  int j   = q % 50;            // chunk within unit
  int ug  = q / 50;            // 0..63
  int u   = ug*8 + xcd;        // 0..511  (b,c2)
  int b   = u >> 5;            // /32
  int c2  = u & 31;
  int c   = c2 << 1;

  int idx = j*256 + (int)threadIdx.x;  // 0..12799 within unit
  int n   = idx >> 6;
  int i   = idx & 63;

  int p = (b*NLINES + n)*LLEN + i;     // point index
  int4   o = offs[p];
  float4 w = wts[p];

  const float* f0 = feature + ((size_t)(b*CFEAT + c) << 16);  // plane (b,c)
  const float* f1 = f0 + (1 << 16);                            // plane (b,c+1)

  // issue all 8 gathers, then combine
  float a00 = f0[o.x], a01 = f0[o.y], a02 = f0[o.z], a03 = f0[o.w];
  float a10 = f1[o.x], a11 = f1[o.y], a12 = f1[o.z], a13 = f1[o.w];
  float v0 = w.x*a00 + w.y*a01 + w.z*a02 + w.w*a03;
  float v1 = w.x*a10 + w.y*a11 + w.z*a12 + w.w*a13;

  size_t ob = (size_t)O_FEAT + (((size_t)(b*CFEAT + c))*NLINES + n)*LLEN + i;
  out[ob] = v0;
  out[ob + (size_t)(NLINES*LLEN)] = v1;
}

// Fallback feature kernel (R2 structure), used only if ws is too small.
__global__ __launch_bounds__(256)
void contour_feature_kernel(const float* __restrict__ feature,
                            const float* __restrict__ pose,
                            const float* __restrict__ cam,
                            const float* __restrict__ tv,
                            float* __restrict__ out)
{
  int ln = blockIdx.x;
  int n  = ln % NLINES;
  int b  = ln / NLINES;
  int t  = threadIdx.x;
  int i  = t & 63;
  int w  = t >> 6;

  LineGeom g = compute_line(pose, cam, tv, b, n);
  float x, y;
  point_xy(g, i, x, y);

  float x0f = floorf(x), y0f = floorf(y);
  float wx1 = x - x0f, wy1 = y - y0f;
  float wx0 = 1.0f - wx1, wy0 = 1.0f - wy1;
  int x0 = (int)x0f, y0 = (int)y0f;
  int x1 = x0 + 1,  y1 = y0 + 1;
  bool vx0 = (x0 >= 0) && (x0 < WIMG);
  bool vx1 = (x1 >= 0) && (x1 < WIMG);
  bool vy0 = (y0 >= 0) && (y0 < HIMG);
  bool vy1 = (y1 >= 0) && (y1 < HIMG);
  float w00 = wx0*wy0 * ((vx0 && vy0) ? 1.f : 0.f);
  float w10 = wx1*wy0 * ((vx1 && vy0) ? 1.f : 0.f);
  float w01 = wx0*wy1 * ((vx0 && vy1) ? 1.f : 0.f);
  float w11 = wx1*wy1 * ((vx1 && vy1) ? 1.f : 0.f);
  int xc0 = min(max(x0,0), WIMG-1), xc1 = min(max(x1,0), WIMG-1);
  int yc0 = min(max(y0,0), HIMG-1), yc1 = min(max(y1,0), HIMG-1);
  int off00 = yc0*WIMG + xc0;
  int off10 = yc0*WIMG + xc1;
  int off01 = yc1*WIMG + xc0;
  int off11 = yc1*WIMG + xc1;

  const float* fbase = feature + (size_t)b*CFEAT*HIMG*WIMG;
  size_t obase = (size_t)O_FEAT + (((size_t)b*CFEAT)*NLINES + n)*LLEN + i;

  #pragma unroll
  for (int k = 0; k < 16; ++k) {
    int c = w*16 + k;
    const float* fc = fbase + (size_t)c*HIMG*WIMG;
    float val = w00*fc[off00] + w10*fc[off10]
              + w01*fc[off01] + w11*fc[off11];
    out[obase + (size_t)c*NLINES*LLEN] = val;
  }
}

extern "C" void kernel_launch(void* const* d_in, const int* in_sizes, int n_in,
                              void* d_out, int out_size, void* d_ws, size_t ws_size,
                              hipStream_t stream) {
  const float* image   = (const float*)d_in[0];
  const float* feature = (const float*)d_in[1];
  const float* pose    = (const float*)d_in[2];
  const float* cam     = (const float*)d_in[3];
  const float* tv      = (const float*)d_in[4];
  const float* fore    = (const float*)d_in[5];
  const float* back    = (const float*)d_in[6];
  float* out = (float*)d_out;

  const size_t need = (size_t)NPTS * (sizeof(int4) + sizeof(float4)); // 6.55 MB
  if (ws_size >= need) {
    int4*   offs = (int4*)d_ws;
    float4* wts  = (float4*)((char*)d_ws + (size_t)NPTS*sizeof(int4));
    contour_points_pre_kernel<<<NPTS/256, 256, 0, stream>>>(
        image, pose, cam, tv, fore, back, out, offs, wts);
    // 13107200 elems / 2 per thread / 256 = 25600 blocks
    contour_gather2_kernel<<<(BN*CFEAT*NLINES*LLEN)/(2*256), 256, 0, stream>>>(
        feature, offs, wts, out);
  } else {
    contour_points_kernel<<<NPTS/256, 256, 0, stream>>>(
        image, pose, cam, tv, fore, back, out);
    contour_feature_kernel<<<BN*NLINES, 256, 0, stream>>>(
        feature, pose, cam, tv, out);
  }
}